// Round 1
// baseline (89.159 us; speedup 1.0000x reference)
//
#include <hip/hip_runtime.h>
#include <math.h>

// Problem constants (from reference): K=32 components, D=16 dims,
// component stride = 1 + D + D(D+1)/2 = 153 floats, row = 32*153 = 4896 floats.
#define KCOMP   32
#define DDIM    16
#define CSTRIDE 153
#define ROWF    (KCOMP * CSTRIDE)     // 4896 floats per batch row
#define ROWB    (ROWF * 4)            // 19584 bytes per batch row
#define TROWS   2                     // batch rows per wave (one per half-wave)
#define TILE_B  (TROWS * ROWB)        // 39168 bytes staged per block
#define NLD16   (TILE_B / 1024)       // 38 full 1KB global_load_lds
#define REMB    (TILE_B - NLD16*1024) // 256 bytes remainder (64 lanes x 4B)

// async global->LDS, linear layout (wave-uniform LDS base + lane*size)
#define GLOAD_LDS16(gsrc, ldst)                                                \
    __builtin_amdgcn_global_load_lds(                                          \
        (const __attribute__((address_space(1))) void*)(gsrc),                 \
        (__attribute__((address_space(3))) void*)(ldst), 16, 0, 0)
#define GLOAD_LDS4(gsrc, ldst)                                                 \
    __builtin_amdgcn_global_load_lds(                                          \
        (const __attribute__((address_space(1))) void*)(gsrc),                 \
        (__attribute__((address_space(3))) void*)(ldst), 4, 0, 0)

__global__ __launch_bounds__(64)
void mdn_logp_kernel(const float* __restrict__ p,
                     const float* __restrict__ y,
                     float* __restrict__ out)
{
    __shared__ float lds[TROWS * ROWF];   // 39168 B -> 4 blocks/CU

    const int  lane = threadIdx.x & 63;
    const long tile = blockIdx.x;

    // ---- stage 2 contiguous batch rows of p into LDS, fully coalesced ----
    const char* g = (const char*)p + tile * (long)TILE_B;
    char* l = (char*)lds;
    #pragma unroll
    for (int c = 0; c < NLD16; ++c) {
        GLOAD_LDS16(g + c * 1024 + lane * 16, l + c * 1024);
    }
    GLOAD_LDS4(g + NLD16 * 1024 + lane * 4, l + NLD16 * 1024);

    asm volatile("s_waitcnt vmcnt(0)" ::: "memory");
    // single wave per block: vmcnt(0) suffices, no barrier needed

    // ---- per-lane: half-wave r owns row 2*tile+r, lane k owns component k ----
    const int  r   = lane >> 5;
    const int  k   = lane & 31;
    const long row = tile * TROWS + r;

    const float* comp = &lds[r * ROWF + k * CSTRIDE]; // word-stride 153 (odd) -> bank-conflict-free
    const float* yr   = y + row * DDIM;

    const float pi_v = comp[0];

    // diff = y - loc   (y is 16B-aligned: vectorize)
    float diff[DDIM];
    {
        const float4* y4 = (const float4*)yr;
        float4 v0 = y4[0], v1 = y4[1], v2 = y4[2], v3 = y4[3];
        float yv[DDIM] = { v0.x, v0.y, v0.z, v0.w,  v1.x, v1.y, v1.z, v1.w,
                           v2.x, v2.y, v2.z, v2.w,  v3.x, v3.y, v3.z, v3.w };
        #pragma unroll
        for (int d = 0; d < DDIM; ++d) diff[d] = yv[d] - comp[1 + d];
    }

    // ---- streaming forward substitution: z = L^-1 diff ----
    // st_par is stored row-major over tril(i,j): idx(i,j) = i(i+1)/2 + j
    const float* st = comp + 1 + DDIM;
    float z[DDIM];
    float sumsq = 0.0f, hld = 0.0f;
    int idx = 0;
    #pragma unroll
    for (int i = 0; i < DDIM; ++i) {
        float acc = diff[i];
        #pragma unroll
        for (int j = 0; j < i; ++j)
            acc = fmaf(-st[idx + j], z[j], acc);
        float dr = fmaxf(st[idx + i], -15.0f);
        // stable softplus: max(x,0) + log1p(exp(-|x|))
        float sp = fmaxf(dr, 0.0f) + log1pf(expf(-fabsf(dr)));
        float zi = acc / sp;
        z[i] = zi;
        sumsq = fmaf(zi, zi, sumsq);
        hld += logf(sp);
        idx += i + 1;
    }

    const float LOG_2PI = 1.8378770664093453f;
    const float clp = -0.5f * (sumsq + (float)DDIM * LOG_2PI) - hld;
    const float lw  = fmaxf(pi_v, -15.0f);
    const float a   = lw + clp;

    // ---- logsumexp over the 32 components (within each half-wave) ----
    // out = LSE(lw + clp) - LSE(lw)   (== LSE(log_softmax(pi) + clp))
    float m_a = a, m_w = lw;
    #pragma unroll
    for (int s = 16; s > 0; s >>= 1) {
        m_a = fmaxf(m_a, __shfl_xor(m_a, s, 32));
        m_w = fmaxf(m_w, __shfl_xor(m_w, s, 32));
    }
    float e_a = expf(a  - m_a);
    float e_w = expf(lw - m_w);
    #pragma unroll
    for (int s = 16; s > 0; s >>= 1) {
        e_a += __shfl_xor(e_a, s, 32);
        e_w += __shfl_xor(e_w, s, 32);
    }

    if (k == 0)
        out[row] = (m_a + logf(e_a)) - (m_w + logf(e_w));
}

extern "C" void kernel_launch(void* const* d_in, const int* in_sizes, int n_in,
                              void* d_out, int out_size, void* d_ws, size_t ws_size,
                              hipStream_t stream) {
    (void)n_in; (void)d_ws; (void)ws_size;
    const float* p = (const float*)d_in[0];
    const float* y = (const float*)d_in[1];
    float* out = (float*)d_out;

    const int B = out_size;            // 16384 batch rows
    const int tiles = B / TROWS;       // 8192 blocks, 1 wave each
    mdn_logp_kernel<<<tiles, 64, 0, stream>>>(p, y, out);
}